// Round 7
// baseline (15865.308 us; speedup 1.0000x reference)
//
#include <hip/hip_runtime.h>
#include <hip/hip_bf16.h>
#include <hip/hip_fp16.h>
#include <math.h>

#define DIN   1068
#define DPAD  1088
#define HID   768
#define G4    3072
#define NWG_SCAN 96
#define SLAB  2048
#define HPAD  776   // 768 + 8 halfs pad for scan LDS
#define GBM   128
#define GBN   128
#define AROWP 40    // LDS row pitch in halfs: 32 + 8 pad

typedef _Float16 half8 __attribute__((ext_vector_type(8)));
typedef float    floatx4 __attribute__((ext_vector_type(4)));

__device__ __forceinline__ float sigf(float x){ return 1.0f/(1.0f + expf(-x)); }

// ---------------- prep: doc offsets -> per-position index within doc ----------------
__global__ void k_prep(const int* __restrict__ doc_lens, int* __restrict__ pos_idx, int N){
    __shared__ int off[129];
    if (threadIdx.x == 0){
        int a = 0;
        for (int d = 0; d < 128; ++d){ off[d] = a; a += doc_lens[d]; }
        off[128] = a;
    }
    __syncthreads();
    for (int d = threadIdx.x; d < 128; d += blockDim.x){
        int s = off[d], e = off[d+1];
        for (int n = s; n < e && n < N; ++n) pos_idx[n] = n - s;
    }
}

// ---------------- x_doc = x + PE(pos) (fp32), rows offset +4, cols 1068->1088 ----------------
__global__ void k_fill_xdoc(const float* __restrict__ x, const int* __restrict__ pos_idx,
                            float* __restrict__ xd, int N){
    int idx = blockIdx.x*256 + threadIdx.x;
    int total = N * DPAD;
    if (idx >= total) return;
    int n = idx / DPAD;
    int d = idx - n*DPAD;
    float v = 0.f;
    if (d < DIN){
        int pos = pos_idx[n];
        int i2 = d & ~1;                      // 2*i for both sin (even d) and cos (odd d)
        float ex  = expf(-(float)i2 * (9.210340371976184f / 1068.0f)); // 10000^(-i2/1068)
        float ang = (float)pos * ex;
        v = x[(size_t)n*DIN + d] + ((d & 1) ? cosf(ang) : sinf(ang));
    }
    xd[(size_t)(n+4)*DPAD + d] = v;
}

// ---------------- repack conv weights [oc][d][t] -> [tau][oc][dpad] (fp32) ----------------
__global__ void k_repack_w(const float* __restrict__ w0, const float* __restrict__ w1,
                           const float* __restrict__ w2, float* __restrict__ wrep){
    int idx = blockIdx.x*256 + threadIdx.x;
    const int total = 15*256*DPAD;
    if (idx >= total) return;
    int d    = idx % DPAD;
    int rest = idx / DPAD;
    int oc   = rest % 256;
    int tau  = rest / 256;
    const float* w; int k, t;
    if (tau < 3)      { w = w0; k = 3; t = tau;     }
    else if (tau < 8) { w = w1; k = 5; t = tau - 3; }
    else              { w = w2; k = 7; t = tau - 8; }
    float v = 0.f;
    if (d < DIN) v = w[((size_t)oc*DIN + d)*k + t];
    wrep[(size_t)idx] = v;
}

// ---------------- MFMA tile core over fp32 operands ----------------
// A,B fp32 row-major [*, K]; B pre-offset to its 128-row block. K % 32 == 0.
// Staging converts fp32 -> fp16 {hi[,lo]} in LDS. SPLIT=true computes
// hi*hi + hi*lo + lo*hi (3 MFMAs, fp32-equivalent precision, rel err ~2^-22);
// SPLIT=false computes hi*hi only (plain fp16 precision).
// 256 thr = 4 waves in 2x2, per-wave 64x64 output as 4x4 frags of 16x16x32_f16.
// Operand layout validated on HW by rounds 1-3: A/B lane l: row (l&15), k-base
// (l>>4)*8; D: col = lane&15, row = (lane>>4)*4 + r.
template<bool SPLIT>
__device__ __forceinline__ void mfma_core(
    const float* __restrict__ A, const float* __restrict__ B, int K,
    int m0, int shift, int rowcap, int tid, floatx4 (&acc)[4][4],
    _Float16* __restrict__ Ahi, _Float16* __restrict__ Alo,
    _Float16* __restrict__ Bhi, _Float16* __restrict__ Blo)
{
    const int st_r = tid >> 1;            // staged row 0..127
    const int st_s = (tid & 1) * 16;      // k-offset 0 or 16 (floats)
    const int wv = tid >> 6, lane = tid & 63;
    const int wr = wv >> 1, wc = wv & 1;
    const int mloc = lane & 15, kb = lane >> 4;
    for (int k0 = 0; k0 < K; k0 += 32){
        // ---- stage A (guarded rows) ----
        {
            float av[16] = {};
            int r = m0 + st_r + shift;
            if ((unsigned)r < (unsigned)rowcap){
                const float* pa = A + (size_t)r*K + k0 + st_s;
                *(float4*)&av[0]  = *(const float4*)pa;
                *(float4*)&av[4]  = *(const float4*)(pa+4);
                *(float4*)&av[8]  = *(const float4*)(pa+8);
                *(float4*)&av[12] = *(const float4*)(pa+12);
            }
            #pragma unroll
            for (int g = 0; g < 2; ++g){
                half8 hh, hl;
                #pragma unroll
                for (int e = 0; e < 8; ++e){
                    float f = av[g*8+e];
                    _Float16 h = (_Float16)f;
                    hh[e] = h;
                    if (SPLIT) hl[e] = (_Float16)(f - (float)h);
                }
                *(half8*)&Ahi[st_r*AROWP + st_s + g*8] = hh;
                if (SPLIT) *(half8*)&Alo[st_r*AROWP + st_s + g*8] = hl;
            }
        }
        // ---- stage B (always valid) ----
        {
            float bv[16];
            const float* pb = B + (size_t)st_r*K + k0 + st_s;
            *(float4*)&bv[0]  = *(const float4*)pb;
            *(float4*)&bv[4]  = *(const float4*)(pb+4);
            *(float4*)&bv[8]  = *(const float4*)(pb+8);
            *(float4*)&bv[12] = *(const float4*)(pb+12);
            #pragma unroll
            for (int g = 0; g < 2; ++g){
                half8 hh, hl;
                #pragma unroll
                for (int e = 0; e < 8; ++e){
                    float f = bv[g*8+e];
                    _Float16 h = (_Float16)f;
                    hh[e] = h;
                    if (SPLIT) hl[e] = (_Float16)(f - (float)h);
                }
                *(half8*)&Bhi[st_r*AROWP + st_s + g*8] = hh;
                if (SPLIT) *(half8*)&Blo[st_r*AROWP + st_s + g*8] = hl;
            }
        }
        __syncthreads();
        half8 afh[4], bfh[4], afl[4], bfl[4];
        #pragma unroll
        for (int i = 0; i < 4; ++i){
            afh[i] = *(const half8*)&Ahi[(wr*64 + i*16 + mloc)*AROWP + kb*8];
            bfh[i] = *(const half8*)&Bhi[(wc*64 + i*16 + mloc)*AROWP + kb*8];
            if (SPLIT){
                afl[i] = *(const half8*)&Alo[(wr*64 + i*16 + mloc)*AROWP + kb*8];
                bfl[i] = *(const half8*)&Blo[(wc*64 + i*16 + mloc)*AROWP + kb*8];
            }
        }
        #pragma unroll
        for (int i = 0; i < 4; ++i)
            #pragma unroll
            for (int j = 0; j < 4; ++j){
                acc[i][j] = __builtin_amdgcn_mfma_f32_16x16x32_f16(afh[i], bfh[j], acc[i][j], 0, 0, 0);
                if (SPLIT){
                    acc[i][j] = __builtin_amdgcn_mfma_f32_16x16x32_f16(afh[i], bfl[j], acc[i][j], 0, 0, 0);
                    acc[i][j] = __builtin_amdgcn_mfma_f32_16x16x32_f16(afl[i], bfh[j], acc[i][j], 0, 0, 0);
                }
            }
        __syncthreads();
    }
}

// ---------------- split-precision GEMM: C = A0*B0^T + bias0 (+bias1); fp32-quality ----------------
template<bool CHALF>
__global__ __launch_bounds__(256) void k_gemm_split(
    const float* __restrict__ A0, const float* __restrict__ B0,
    const float* __restrict__ bias0, const float* __restrict__ bias1,
    void* __restrict__ C, int M, int K, int ldc)
{
    __shared__ _Float16 Ahi[GBM*AROWP], Alo[GBM*AROWP];
    __shared__ _Float16 Bhi[GBN*AROWP], Blo[GBN*AROWP];
    floatx4 zz = {0.f, 0.f, 0.f, 0.f};
    floatx4 acc[4][4];
    #pragma unroll
    for (int i = 0; i < 4; ++i)
        #pragma unroll
        for (int j = 0; j < 4; ++j) acc[i][j] = zz;
    const int tid = threadIdx.x;
    const int m0 = blockIdx.x*GBM;
    const int n0 = blockIdx.y*GBN;
    mfma_core<true>(A0, B0 + (size_t)n0*K, K, m0, 0, M, tid, acc, Ahi, Alo, Bhi, Blo);
    const int wv = tid >> 6, lane = tid & 63;
    const int wr = wv >> 1, wc = wv & 1;
    const int mloc = lane & 15, kb = lane >> 4;
    float bv[4];
    #pragma unroll
    for (int j = 0; j < 4; ++j){
        int cn = n0 + wc*64 + j*16 + mloc;
        bv[j] = bias0[cn] + (bias1 ? bias1[cn] : 0.f);
    }
    #pragma unroll
    for (int i = 0; i < 4; ++i){
        #pragma unroll
        for (int r = 0; r < 4; ++r){
            int gm = m0 + wr*64 + i*16 + kb*4 + r;
            if (gm >= M) continue;
            #pragma unroll
            for (int j = 0; j < 4; ++j){
                int cn = n0 + wc*64 + j*16 + mloc;
                float v = acc[i][j][r] + bv[j];
                if (CHALF) ((__half*)C)[(size_t)gm*ldc + cn] = __float2half(v);
                else       ((float*)C)[(size_t)gm*ldc + cn] = v;
            }
        }
    }
}

// ---------------- plain fp16 GEMM (fp32 in): C = A0*B0^T + A1*B1^T + bias0 + bias1 ----------------
__global__ __launch_bounds__(256) void k_gemm_plain2(
    const float* __restrict__ A0, const float* __restrict__ B0,
    const float* __restrict__ A1, const float* __restrict__ B1,
    const float* __restrict__ bias0, const float* __restrict__ bias1,
    float* __restrict__ C, int M, int K, int ldc)
{
    __shared__ _Float16 Ahi[GBM*AROWP];
    __shared__ _Float16 Bhi[GBN*AROWP];
    floatx4 zz = {0.f, 0.f, 0.f, 0.f};
    floatx4 acc[4][4];
    #pragma unroll
    for (int i = 0; i < 4; ++i)
        #pragma unroll
        for (int j = 0; j < 4; ++j) acc[i][j] = zz;
    const int tid = threadIdx.x;
    const int m0 = blockIdx.x*GBM;
    const int n0 = blockIdx.y*GBN;
    mfma_core<false>(A0, B0 + (size_t)n0*K, K, m0, 0, M, tid, acc, Ahi, nullptr, Bhi, nullptr);
    mfma_core<false>(A1, B1 + (size_t)n0*K, K, m0, 0, M, tid, acc, Ahi, nullptr, Bhi, nullptr);
    const int wv = tid >> 6, lane = tid & 63;
    const int wr = wv >> 1, wc = wv & 1;
    const int mloc = lane & 15, kb = lane >> 4;
    float bv[4];
    #pragma unroll
    for (int j = 0; j < 4; ++j){
        int cn = n0 + wc*64 + j*16 + mloc;
        bv[j] = bias0[cn] + bias1[cn];
    }
    #pragma unroll
    for (int i = 0; i < 4; ++i){
        #pragma unroll
        for (int r = 0; r < 4; ++r){
            int gm = m0 + wr*64 + i*16 + kb*4 + r;
            if (gm >= M) continue;
            #pragma unroll
            for (int j = 0; j < 4; ++j){
                int cn = n0 + wc*64 + j*16 + mloc;
                C[(size_t)gm*ldc + cn] = acc[i][j][r] + bv[j];
            }
        }
    }
}

// ---------------- conv GEMM (split MFMA) over taps + bias + LeakyReLU -> x_feat fp32 ----------------
__global__ __launch_bounds__(256) void k_conv_gemm(
    const float* __restrict__ xd, const float* __restrict__ wrep,
    const float* __restrict__ cb0, const float* __restrict__ cb1, const float* __restrict__ cb2,
    float* __restrict__ x_feat, int N)
{
    __shared__ _Float16 Ahi[GBM*AROWP], Alo[GBM*AROWP];
    __shared__ _Float16 Bhi[GBN*AROWP], Blo[GBN*AROWP];
    floatx4 zz = {0.f, 0.f, 0.f, 0.f};
    floatx4 acc[4][4];
    #pragma unroll
    for (int i = 0; i < 4; ++i)
        #pragma unroll
        for (int j = 0; j < 4; ++j) acc[i][j] = zz;
    const int tid = threadIdx.x;
    const int m0  = blockIdx.x*GBM;
    const int gid = blockIdx.y;            // 0..5
    const int g = gid >> 1, half = gid & 1;
    const int kg = (g==0)?3:((g==1)?5:7);
    const int p  = kg >> 1;
    const int tb = (g==0)?0:((g==1)?3:8);
    for (int t = 0; t < kg; ++t){
        const float* B = wrep + ((size_t)(tb + t)*256 + half*128)*DPAD;
        mfma_core<true>(xd, B, DPAD, m0, 4 + t - p, N + 8, tid, acc, Ahi, Alo, Bhi, Blo);
    }
    const float* cb = (g==0)?cb0:((g==1)?cb1:cb2);
    const int wv = tid >> 6, lane = tid & 63;
    const int wr = wv >> 1, wc = wv & 1;
    const int mloc = lane & 15, kb = lane >> 4;
    float bv[4];
    #pragma unroll
    for (int j = 0; j < 4; ++j) bv[j] = cb[half*128 + wc*64 + j*16 + mloc];
    const int colbase = g*256 + half*128 + wc*64 + mloc;
    #pragma unroll
    for (int i = 0; i < 4; ++i){
        #pragma unroll
        for (int r = 0; r < 4; ++r){
            int gm = m0 + wr*64 + i*16 + kb*4 + r;
            if (gm >= N) continue;
            float* crow = x_feat + (size_t)gm*HID + colbase;
            #pragma unroll
            for (int j = 0; j < 4; ++j){
                float y = acc[i][j][r] + bv[j];
                crow[j*16] = (y >= 0.f) ? y : 0.01f*y;
            }
        }
    }
}

// ---------------- maxpool (stride1, same) over activated conv output ----------------
__global__ void k_pool(const float* __restrict__ xf, float* __restrict__ xp, int N){
    int idx = blockIdx.x*256 + threadIdx.x;
    if (idx >= N*HID) return;
    int n = idx / HID, ch = idx - n*HID;
    int p = (ch < 256) ? 1 : ((ch < 512) ? 2 : 3);
    float m = -INFINITY;
    for (int d = -p; d <= p; ++d){
        int r = n + d;
        if (0 <= r && r < N) m = fmaxf(m, xf[(size_t)r*HID + ch]);
    }
    xp[idx] = m;
}

// ---------------- chunked LSTM scan: 96 persistent WGs, MFMA h-dot ----------------
// Flagless self-validating exchange: each 64-bit h_buf word = {seq:32 | 2xfp16:32},
// stored with one relaxed agent-scope atomic. Consumers poll the data words
// directly (24/thread, batched loads, straggler re-poll) until seq == s.
// This removes the old protocol's store-drain RTT, flag publish, and separate
// stage load: per-step critical path drops from ~4 MALL RTTs to ~2.
// Race-freedom: a WG reaches step s+1 phase 3 (overwriting parity-s buffer)
// only after seeing ALL WGs' seq-(s+1) words, which requires every WG finished
// its step-s reads -> ping-pong stays safe with no barrier.
// Tail chunks: dead chains (n>=N) store payload 0 with correct seq so pollers
// never hang; h_all/c_all pad rows stay zero (stores still guarded).
__global__ __launch_bounds__(256, 1) void k_scan(
    const __half* __restrict__ G1, const float* __restrict__ W_hh,
    float* __restrict__ h_all, __half* __restrict__ c_all,
    unsigned long long* __restrict__ h_buf,   // 2 x 6144 words
    int N, int n_chunks)
{
    __shared__ __align__(16) __half hs16[16*HPAD];  // [chain][k] fp16, padded rows
    __shared__ float gbuf[2][32][17];               // [kh][row m][chain] partial gates
    const int w    = blockIdx.x;
    const int t    = threadIdx.x;
    const int lane = t & 63;
    const int wv   = t >> 6;              // wave 0..3
    const int mt   = wv & 1;              // M-tile (rows mt*16..mt*16+15)
    const int kh   = wv >> 1;             // K-half (k = kh*384 ..)
    const int mloc = lane & 15;           // A row within tile / B chain
    const int kb   = lane >> 4;           // k-subgroup (8 halfs each)
    const int mg   = mt*16 + mloc;        // local row 0..31
    const int qq   = mg >> 3;             // gate 0..3
    const int il   = mg & 7;              // h-index 0..7
    const int grow = qq*HID + w*8 + il;   // global W_hh row
    half8 areg[12];
    #pragma unroll
    for (int sk = 0; sk < 12; ++sk){
        const float* wp = W_hh + (size_t)grow*HID + kh*384 + sk*32 + kb*8;
        half8 a;
        #pragma unroll
        for (int e = 0; e < 8; ++e) a[e] = (_Float16)wp[e];
        areg[sk] = a;
    }
    float cstate = 0.f;
    const int ci = t >> 4;                // cell-phase h index (t<128)
    const int cc = t & 15;                // cell-phase chain
    const int st_row = t >> 4;            // staging chain row 0..15
    for (int s = 0; s < n_chunks; ++s){
        // 0. prefetch this step's G1 gates (independent of h -> overlaps the poll)
        float g1v0=0.f, g1v1=0.f, g1v2=0.f, g1v3=0.f;
        int n = s*16 + cc;
        if (t < 128 && n < N){
            const __half* g1r = G1 + (size_t)n*G4 + w*8 + ci;
            g1v0 = __half2float(g1r[0]);
            g1v1 = __half2float(g1r[HID]);
            g1v2 = __half2float(g1r[2*HID]);
            g1v3 = __half2float(g1r[3*HID]);
        }
        // 1. poll-stage h: 24 self-validating words per thread (batched, re-poll
        //    stragglers), then pack payloads into LDS.
        {
            const unsigned want = (unsigned)s;
            const unsigned long long* src =
                h_buf + (size_t)(s & 1)*6144 + (size_t)t*24;
            unsigned long long v[24];
            #pragma unroll
            for (int i = 0; i < 24; ++i)
                v[i] = __hip_atomic_load(src + i, __ATOMIC_RELAXED,
                                         __HIP_MEMORY_SCOPE_AGENT);
            for (;;){
                bool ok = true;
                #pragma unroll
                for (int i = 0; i < 24; ++i)
                    ok &= ((unsigned)(v[i] >> 32) == want);
                if (ok) break;
                __builtin_amdgcn_s_sleep(1);
                #pragma unroll
                for (int i = 0; i < 24; ++i)
                    if ((unsigned)(v[i] >> 32) != want)
                        v[i] = __hip_atomic_load(src + i, __ATOMIC_RELAXED,
                                                 __HIP_MEMORY_SCOPE_AGENT);
            }
            unsigned long long* hrow =
                (unsigned long long*)(hs16 + (size_t)st_row*HPAD) + (t & 15)*12;
            #pragma unroll
            for (int i = 0; i < 12; ++i)
                hrow[i] = (v[2*i] & 0xffffffffull) | (v[2*i+1] << 32);
        }
        __syncthreads();
        // 2. MFMA: gates partial over this wave's K-half
        {
            floatx4 acc = {0.f, 0.f, 0.f, 0.f};
            const _Float16* hb = (const _Float16*)hs16;
            #pragma unroll
            for (int sk = 0; sk < 12; ++sk){
                int k0 = kh*384 + sk*32 + kb*8;
                half8 b = *(const half8*)(hb + (size_t)mloc*HPAD + k0);
                acc = __builtin_amdgcn_mfma_f32_16x16x32_f16(areg[sk], b, acc, 0, 0, 0);
            }
            #pragma unroll
            for (int r = 0; r < 4; ++r)
                gbuf[kh][mt*16 + kb*4 + r][mloc] = acc[r];
        }
        __syncthreads();
        // 3. cell math: 128 threads = 8 h-indices x 16 chains; seq-tagged store
        if (t < 128){
            float h2 = 0.f;
            if (n < N){
                int col = w*8 + ci;
                float gI = gbuf[0][0*8+ci][cc] + gbuf[1][0*8+ci][cc] + g1v0;
                float gF = gbuf[0][1*8+ci][cc] + gbuf[1][1*8+ci][cc] + g1v1;
                float gG = gbuf[0][2*8+ci][cc] + gbuf[1][2*8+ci][cc] + g1v2;
                float gO = gbuf[0][3*8+ci][cc] + gbuf[1][3*8+ci][cc] + g1v3;
                float c2 = sigf(gF)*cstate + sigf(gI)*tanhf(gG);
                h2 = sigf(gO)*tanhf(c2);
                cstate = c2;
                size_t rowoff = (size_t)(16 + n)*HID + col;
                h_all[rowoff] = h2;                       // fp32 (phase-4 GEMM input)
                c_all[rowoff] = __float2half(c2);
            }
            unsigned hb2 = (unsigned)__half_as_ushort(__float2half(h2));
            unsigned other = __shfl_xor(hb2, 16, 64);  // partner t^16 = same cc, ci^1
            if ((ci & 1) == 0){
                unsigned pk = hb2 | (other << 16);     // even col = low half
                unsigned long long word =
                    (unsigned long long)pk |
                    ((unsigned long long)(unsigned)(s + 1) << 32);
                unsigned long long* dst =
                    h_buf + (size_t)((s+1) & 1)*6144 +
                    (size_t)cc*384 + (size_t)w*4 + (ci >> 1);
                __hip_atomic_store(dst, word, __ATOMIC_RELAXED,
                                   __HIP_MEMORY_SCOPE_AGENT);
            }
        }
        // no inter-WG barrier: the seq tags carry the synchronization.
    }
}

// ---------------- final two LSTM cells (forward + rev weights) ----------------
__global__ void k_cell(const float* __restrict__ g2, const float* __restrict__ g3,
                       const __half* __restrict__ c_all, float* __restrict__ out,
                       int n0, int Mslab, int N){
    int idx = blockIdx.x*256 + threadIdx.x;
    if (idx >= Mslab*HID) return;
    int nl = idx / HID, j = idx - nl*HID;
    int n = n0 + nl;
    const float* r2 = g2 + (size_t)nl*G4;
    float cp = __half2float(c_all[(size_t)(7 + n)*HID + j]);   // c[n-9] (16-row pad, -9)
    float c2 = sigf(r2[HID + j])*cp + sigf(r2[j])*tanhf(r2[2*HID + j]);
    out[(size_t)n*1536 + j] = sigf(r2[3*HID + j])*tanhf(c2);
    const float* r3 = g3 + (size_t)nl*G4;
    float cn = __half2float(c_all[(size_t)(25 + n)*HID + j]);  // c[n+9]
    float c3 = sigf(r3[HID + j])*cn + sigf(r3[j])*tanhf(r3[2*HID + j]);
    out[(size_t)n*1536 + HID + j] = sigf(r3[3*HID + j])*tanhf(c3);
}

extern "C" void kernel_launch(void* const* d_in, const int* in_sizes, int n_in,
                              void* d_out, int out_size, void* d_ws, size_t ws_size,
                              hipStream_t stream)
{
    const float* x     = (const float*)d_in[0];
    const int*   dl    = (const int*)  d_in[1];
    const float* cw0   = (const float*)d_in[2];
    const float* cb0   = (const float*)d_in[3];
    const float* cw1   = (const float*)d_in[4];
    const float* cb1   = (const float*)d_in[5];
    const float* cw2   = (const float*)d_in[6];
    const float* cb2   = (const float*)d_in[7];
    const float* W_ih  = (const float*)d_in[8];
    const float* W_hh  = (const float*)d_in[9];
    const float* b_ih  = (const float*)d_in[10];
    const float* b_hh  = (const float*)d_in[11];
    const float* W_ihr = (const float*)d_in[12];
    const float* W_hhr = (const float*)d_in[13];
    const float* b_ihr = (const float*)d_in[14];
    const float* b_hhr = (const float*)d_in[15];
    float* out = (float*)d_out;
    (void)in_sizes; (void)n_in;
    const int N = out_size / (2*HID);
    if (N <= 0) return;
    const int n_chunks = (N + 15)/16;
    const int N16 = n_chunks*16;

    // ---- lifetime-overlaid arena (fp32 activations) ----
    // R0 timeline: {xd fp32 + wrep fp32} -> {x_pool fp32} -> {h_all fp32 + c_all fp16}
    auto AL = [](size_t b){ return (b + 255) & ~(size_t)255; };
    const size_t szXd   = AL((size_t)(N+8)*DPAD*4);      // fp32 x_doc
    const size_t szW    = AL((size_t)15*256*DPAD*4);     // conv weights repacked fp32
    const size_t szPool = AL((size_t)N*HID*4);           // x_pool fp32
    const size_t szH    = AL((size_t)(N+32)*HID*4);      // h_all fp32
    const size_t szC    = AL((size_t)(N+32)*HID*2);      // c_all fp16
    size_t r0 = szXd + szW;
    if (szPool     > r0) r0 = szPool;
    if (szH + szC  > r0) r0 = szH + szC;
    const size_t szF    = AL((size_t)N*HID*4);           // x_feat fp32 (alive to end)
    size_t szG1 = AL((size_t)N16*G4*2);                  // fp16 G1 | later g2+g3 fp32
    const size_t szGG   = AL((size_t)SLAB*G4*4);
    if (2*szGG > szG1) szG1 = 2*szGG;
    const size_t szHB   = AL((size_t)2*6144*8);          // h ping-pong (seq-tagged words)
    const size_t szPI   = AL((size_t)N*4);               // pos_idx

    char* wsb = (char*)d_ws;
    size_t off = 0;
    char* R0   = wsb;              off += r0;
    char* pF   = wsb + off;        off += szF;
    char* pG1  = wsb + off;        off += szG1;
    char* pHB  = wsb + off;        off += szHB;
    char* pPI  = wsb + off;        off += szPI;
    if (off > ws_size) return;     // workspace too small: fail loud (wrong answer), not a fault

    float*              xd    = (float*)R0;
    float*              wrep  = (float*)(R0 + szXd);
    float*              x_pool= (float*)R0;              // overlays xd/wrep after conv
    float*              h_all = (float*)R0;              // overlays x_pool after G1 GEMM
    __half*             c_all = (__half*)(R0 + szH);     // beside h_all in R0 slack
    float*              x_feat= (float*)pF;
    __half*             G1    = (__half*)pG1;
    float*              g2    = (float*)pG1;             // overlays G1 after scan
    float*              g3    = (float*)(pG1 + szGG);
    unsigned long long* h_buf = (unsigned long long*)pHB;
    int*                pos_idx = (int*)pPI;

    // ---- phase 1: x_doc fp32 + conv weight repack + conv (split MFMA) + pool ----
    hipMemsetAsync(xd, 0, (size_t)4*DPAD*4, stream);                       // top pad rows
    hipMemsetAsync(xd + (size_t)(N+4)*DPAD, 0, (size_t)4*DPAD*4, stream);  // bottom pad rows
    k_prep<<<1, 128, 0, stream>>>(dl, pos_idx, N);
    k_fill_xdoc<<<(N*DPAD + 255)/256, 256, 0, stream>>>(x, pos_idx, xd, N);
    k_repack_w<<<(15*256*DPAD + 255)/256, 256, 0, stream>>>(cw0, cw1, cw2, wrep);

    const int mt = (N + GBM - 1)/GBM;
    k_conv_gemm<<<dim3(mt, 6), 256, 0, stream>>>(xd, wrep, cb0, cb1, cb2, x_feat, N);
    k_pool<<<(N*HID + 255)/256, 256, 0, stream>>>(x_feat, x_pool, N);      // x_pool overlays xd

    // ---- phase 2: G1 = x_pool*W_ih^T + b_ih + b_hh (split MFMA, fp16 out) ----
    k_gemm_split<true><<<dim3(mt, G4/GBN), 256, 0, stream>>>(
        x_pool, W_ih, b_ih, b_hh, G1, N, HID, G4);

    // ---- phase 3: scan (h_all/c_all overlay x_pool region — pads zeroed only now) ----
    hipMemsetAsync(h_all, 0, (size_t)16*HID*4, stream);
    hipMemsetAsync(h_all + (size_t)(16+N)*HID, 0, (size_t)16*HID*4, stream);
    hipMemsetAsync(c_all, 0, (size_t)16*HID*2, stream);
    hipMemsetAsync(c_all + (size_t)(16+N)*HID, 0, (size_t)16*HID*2, stream);
    hipMemsetAsync(h_buf, 0, szHB, stream);              // seq 0 + zero payload = step-0 input
    k_scan<<<NWG_SCAN, 256, 0, stream>>>(G1, W_hh, h_all, c_all, h_buf, N, n_chunks);

    // ---- phase 4: final two cells, slabbed (g2/g3 overlay G1 region; plain fp16 MFMA) ----
    for (int n0 = 0; n0 < N; n0 += SLAB){
        int ms  = (N - n0 < SLAB) ? (N - n0) : SLAB;
        int mts = (ms + GBM - 1)/GBM;
        k_gemm_plain2<<<dim3(mts, G4/GBN), 256, 0, stream>>>(
            x_feat + (size_t)n0*HID, W_ih, h_all + (size_t)(7+n0)*HID, W_hh,
            b_ih, b_hh, g2, ms, HID, G4);
        k_gemm_plain2<<<dim3(mts, G4/GBN), 256, 0, stream>>>(
            x_feat + (size_t)n0*HID, W_ihr, h_all + (size_t)(25+n0)*HID, W_hhr,
            b_ihr, b_hhr, g3, ms, HID, G4);
        k_cell<<<(ms*HID + 255)/256, 256, 0, stream>>>(g2, g3, c_all, out, n0, ms, N);
    }
}